// Round 1
// 410.239 us; speedup vs baseline: 1.0943x; 1.0943x over previous
//
#include <hip/hip_runtime.h>

// EncoderBlock on MI355X (gfx950). B=2,S=2048,D=1024,H=16,Dh=64.
// Round 9: attention rewritten as 32x32 swapped-operand flash kernel:
//   S^T = mfma_32x32x16(K, Q^T)  -> P lives per-query in registers (no PS LDS)
//   P -> bf16 via pack + v_permlane32_swap_b32 (T12) -> PV B-operand
//   O^T = mfma(V^T, P^T); V^T already produced by the QKV GEMM
//   K/V^T LDS XOR-swizzled (T2, via pre-swizzled gl2lds source), double-
//   buffered with counted s_waitcnt vmcnt(4) + raw s_barrier (T3/T4).

#define DEV __device__ __forceinline__

typedef unsigned short u16;
typedef unsigned int u32;
typedef __attribute__((ext_vector_type(8))) short bfrag;    // 8 bf16 payload
typedef __attribute__((ext_vector_type(8))) __bf16 bf16x8;  // MFMA operand type
typedef __attribute__((ext_vector_type(2))) __bf16 bf16x2_t;
typedef __attribute__((ext_vector_type(4))) unsigned int u32x4;
typedef __attribute__((ext_vector_type(4))) float facc;     // 16x16 MFMA C/D
typedef __attribute__((ext_vector_type(16))) float facc16;  // 32x32 MFMA C/D

DEV float bf2f(u16 u) {
  unsigned int x = ((unsigned int)u) << 16;
  return __builtin_bit_cast(float, x);
}
DEV u16 f2bf(float f) {
  unsigned int x = __builtin_bit_cast(unsigned int, f);
  x += 0x7fffu + ((x >> 16) & 1u);  // RNE
  return (u16)(x >> 16);
}

DEV void gl2lds16(const u16* g, u16* l) {
  // async global->LDS DMA, 16B/lane; LDS dest = wave-uniform base + lane*16
  auto gp = (const __attribute__((address_space(1))) unsigned int*)(g);
  auto lp = (__attribute__((address_space(3))) unsigned int*)(l);
  __builtin_amdgcn_global_load_lds(gp, lp, 16, 0, 0);
}

DEV facc mfma16(bfrag a, bfrag b, facc c) {
  return __builtin_amdgcn_mfma_f32_16x16x32_bf16(
      __builtin_bit_cast(bf16x8, a), __builtin_bit_cast(bf16x8, b), c, 0, 0, 0);
}

DEV facc16 mfma32(bfrag a, bfrag b, facc16 c) {
  return __builtin_amdgcn_mfma_f32_32x32x16_bf16(
      __builtin_bit_cast(bf16x8, a), __builtin_bit_cast(bf16x8, b), c, 0, 0, 0);
}

DEV u32 pk2(float a, float b) {  // pack 2 f32 -> 2 bf16 (RNE, v_cvt_pk path)
  bf16x2_t v;
  v[0] = (__bf16)a;
  v[1] = (__bf16)b;
  return __builtin_bit_cast(u32, v);
}

DEV void pswap(u32& a, u32& b) {  // a' = {a.lo, b.lo}; b' = {a.hi, b.hi}
  asm volatile("v_permlane32_swap_b32 %0, %1" : "+v"(a), "+v"(b));
}

// ---------------------------------------------------------------------------
// Merged prep: qkv transpose (jobs 0..3071), W1T (3072..7167),
// W2T (7168..11263), x cast (11264..15359). All fp32 -> bf16.
// ---------------------------------------------------------------------------
__global__ __launch_bounds__(256) void prep_kernel(
    const float* __restrict__ Wq, const float* __restrict__ Wk,
    const float* __restrict__ Wv, u16* __restrict__ WqkvT,
    const float* __restrict__ W1, u16* __restrict__ W1T,
    const float* __restrict__ W2, u16* __restrict__ W2T,
    const float* __restrict__ x, u16* __restrict__ xb) {
  __shared__ float tile[32][33];
  const int job = blockIdx.x;
  const int tr = threadIdx.x >> 5, tc = threadIdx.x & 31;

  if (job >= 11264) {  // cast x
    const int i = (job - 11264) * 1024 + threadIdx.x * 4;
    const float4 v = *(const float4*)(x + i);
    ushort4 o;
    o.x = f2bf(v.x); o.y = f2bf(v.y); o.z = f2bf(v.z); o.w = f2bf(v.w);
    *(ushort4*)(xb + i) = o;
    return;
  }

  const float* in;
  u16* out;
  int C, R, c0, r0;
  if (job < 3072) {  // qkv: [H][1024][64] -> rows which*1024+h*64+e, cols d
    const int z = job >> 6, rem = job & 63;
    const int which = z >> 4, h = z & 15;
    in = ((which == 0) ? Wq : (which == 1) ? Wk : Wv) + (size_t)h * 1024 * 64;
    out = WqkvT + ((size_t)which * 1024 + h * 64) * 1024;
    C = 64; R = 1024;
    c0 = (rem & 1) * 32; r0 = (rem >> 1) * 32;
  } else if (job < 7168) {  // W1 [1024][4096] -> W1T [4096][1024]
    const int rem = job - 3072;
    in = W1; out = W1T; C = 4096; R = 1024;
    c0 = (rem & 127) * 32; r0 = (rem >> 7) * 32;
  } else {  // W2 [4096][1024] -> W2T [1024][4096]
    const int rem = job - 7168;
    in = W2; out = W2T; C = 1024; R = 4096;
    c0 = (rem & 31) * 32; r0 = (rem >> 5) * 32;
  }
#pragma unroll
  for (int k = 0; k < 4; k++)
    tile[tr + 8 * k][tc] = in[(size_t)(r0 + tr + 8 * k) * C + c0 + tc];
  __syncthreads();
#pragma unroll
  for (int k = 0; k < 4; k++)
    out[(size_t)(c0 + tr + 8 * k) * R + r0 + tc] = f2bf(tile[tc][tr + 8 * k]);
}

// ---------------------------------------------------------------------------
// GEMM C[M][N] = A[M][K] * Bt[N][K]^T, 128x128 tile, BK=32, single-buffer
// m97 structure. GRID: blockIdx.x = M-tile, blockIdx.y = N-tile, z = K-split.
// MODE 0: QKV scatter +bias -> bf16 (V transposed [bh][e][s], packed stores).
// MODE 1: +bias, ReLU -> bf16.
// MODE 3: split-K partial -> bf16 partial buffer z (out0 + z*M*N).
// ---------------------------------------------------------------------------
template <int MODE>
__global__ __launch_bounds__(256) void gemm_bt(
    const u16* __restrict__ A, int lda, const u16* __restrict__ Bt, int ldb,
    int M, int N, int K,
    const float* __restrict__ bias0, const float* __restrict__ bias1,
    const float* __restrict__ bias2,
    void* __restrict__ out0, void* __restrict__ out1, void* __restrict__ out2) {
  __shared__ __align__(16) u16 As[4 * 128 * 8];  // 8 KB
  __shared__ __align__(16) u16 Bs[4 * 128 * 8];  // 8 KB
  const int tid = threadIdx.x;
  const int lane = tid & 63;
  const int wave = tid >> 6;
  const int laneM = lane & 15, quad = lane >> 4;
  const int m0 = blockIdx.x * 128, n0 = blockIdx.y * 128;
  const int wm = wave & 1, wn = wave >> 1;

  if (MODE == 3) {  // split-K: shift K-origin
    A += (size_t)blockIdx.z * K;
    Bt += (size_t)blockIdx.z * K;
  }

  facc acc[4][4] = {};

  for (int k0 = 0; k0 < K; k0 += 32) {
    __syncthreads();  // previous tile's readers done
#pragma unroll
    for (int t = 0; t < 2; t++) {
      const int c0 = t * 256 + wave * 64;  // wave-uniform chunk base
      const int kc = c0 >> 7, r0 = c0 & 127;
      gl2lds16(A + (size_t)(m0 + r0 + lane) * lda + (k0 + kc * 8),
               As + (size_t)c0 * 8);
      gl2lds16(Bt + (size_t)(n0 + r0 + lane) * ldb + (k0 + kc * 8),
               Bs + (size_t)c0 * 8);
    }
    __syncthreads();  // staging visible

    bfrag af[4], bfv[4];
#pragma unroll
    for (int i = 0; i < 4; i++)
      af[i] = *(const bfrag*)(As + (quad * 128 + wm * 64 + i * 16 + laneM) * 8);
#pragma unroll
    for (int j = 0; j < 4; j++)
      bfv[j] = *(const bfrag*)(Bs + (quad * 128 + wn * 64 + j * 16 + laneM) * 8);
#pragma unroll
    for (int i = 0; i < 4; i++)
#pragma unroll
      for (int j = 0; j < 4; j++)
        acc[i][j] = mfma16(af[i], bfv[j], acc[i][j]);
  }

  // epilogue: C/D layout col=lane&15, row=quad*4+v
#pragma unroll
  for (int i = 0; i < 4; i++) {
#pragma unroll
    for (int j = 0; j < 4; j++) {
      const int col = n0 + wn * 64 + j * 16 + laneM;
      const int row0 = m0 + wm * 64 + i * 16 + quad * 4;
      if (MODE == 0) {
        const int which = col >> 10, c = col & 1023;
        const float* bp = (which == 0) ? bias0 : (which == 1) ? bias1 : bias2;
        u16* op = (u16*)((which == 0) ? out0 : (which == 1) ? out1 : out2);
        const float bb = bp[c];
        const int b = row0 >> 11, s0 = row0 & 2047;
        const int h = c >> 6, e = c & 63;
        if (which == 2) {  // V^T [bh][e][s]: 4 consecutive s -> one 8B store
          ushort4 pk;
          pk.x = f2bf(acc[i][j][0] + bb);
          pk.y = f2bf(acc[i][j][1] + bb);
          pk.z = f2bf(acc[i][j][2] + bb);
          pk.w = f2bf(acc[i][j][3] + bb);
          *(ushort4*)(op + ((size_t)((b * 16 + h) * 64 + e)) * 2048 + s0) = pk;
        } else {
#pragma unroll
          for (int v = 0; v < 4; v++)
            op[((size_t)(b * 16 + h) * 2048 + s0 + v) * 64 + e] =
                f2bf(acc[i][j][v] + bb);
        }
      } else if (MODE == 1) {
        const float bb = bias0[col];
#pragma unroll
        for (int v = 0; v < 4; v++)
          ((u16*)out0)[(size_t)(row0 + v) * N + col] =
              f2bf(fmaxf(acc[i][j][v] + bb, 0.0f));
      } else {  // MODE 3: bf16 partial z
        u16* op = (u16*)out0 + (size_t)blockIdx.z * M * N;
#pragma unroll
        for (int v = 0; v < 4; v++)
          op[(size_t)(row0 + v) * N + col] = f2bf(acc[i][j][v]);
      }
    }
  }
}

// ---------------------------------------------------------------------------
// Flash attention, 32x32 swapped-operand structure.
// GRID: x = bh (32), y = Q-tile of 128 rows (16), z = S-half (2).
// 4 waves/block; wave owns 32 queries (q = q0 + wave*32 + (lane&31)).
// Per 64-key step:
//   S^T tile = mfma_32x32x16(K_frag, Q^T_frag): lane holds P[key strip][q],
//     key(reg r) = (r&3) + 8*(r>>2) + 4*(lane>>5).
//   softmax in-register: p = 2^(s*SC + maskbias), lsum accumulates per lane.
//   pack pairs -> bf16, v_permlane32_swap -> P^T B-operand (k = 8*hi + j).
//   O^T += mfma(V^T_frag, P^T_frag).
// K and V^T staged in XOR-swizzled LDS (slot ^= row&7, via pre-swizzled
// gl2lds SOURCE address; LDS dest linear), double-buffered, counted vmcnt(4)
// + raw s_barrier (no vmcnt(0) drain in the main loop).
// Writes unnormalized bf16 O-half and fp32 l-half; ln_attn combines.
// Q,K bf16 [bh][s][64]; V bf16 TRANSPOSED [bh][e][s].
// ---------------------------------------------------------------------------
__global__ __launch_bounds__(256) void attn_kernel(
    const u16* __restrict__ Qb, const u16* __restrict__ Kb,
    const u16* __restrict__ VTg, const int* __restrict__ mask,
    u16* __restrict__ Opart, float* __restrict__ lbuf) {
  __shared__ __align__(16) u16 KT[2][64 * 64];  // 2 x 8 KB, swizzled rows
  __shared__ __align__(16) u16 VS[2][64 * 64];  // 2 x 8 KB, [e][key] swizzled
  __shared__ float MB[1024];                    // additive mask bias (half)
  const int tid = threadIdx.x;
  const int lane = tid & 63;
  const int wave = tid >> 6;
  const int col = lane & 31, hi = lane >> 5;
  const int bh = blockIdx.x, b = bh >> 4, h = bh & 15;
  const int q0 = blockIdx.y * 128;
  const int z = blockIdx.z;
  const int sbase = z * 1024;
  const u16* Qh = Qb + (size_t)bh * 2048 * 64;
  const u16* Kh = Kb + (size_t)bh * 2048 * 64 + (size_t)sbase * 64;
  const u16* Vh = VTg + (size_t)bh * 64 * 2048 + sbase;
  const float SC = 0.125f * 1.4426950408889634f;  // Dh^-0.5 * log2(e)

  // Q fragments (one global read per slice; B-operand: col=q, k=8*hi+j)
  const int q = q0 + wave * 32 + col;
  bfrag qf[4];
#pragma unroll
  for (int ds = 0; ds < 4; ds++)
    qf[ds] = *(const bfrag*)(Qh + (size_t)q * 64 + ds * 16 + 8 * hi);

  // mask -> additive bias table for this half (once per block)
#pragma unroll
  for (int t = 0; t < 4; t++) {
    const int i = t * 256 + tid;
    MB[i] = mask[b * 2048 + sbase + i] ? 0.0f : -1e30f;
  }

  // staging geometry: phys 16B slot s holds logical (row=s>>3, chunk=(s&7)^(row&7))
  const int s0 = wave * 128;  // this wave's 128-slot strip (2 calls of 64)
  const int sl0 = s0 + lane, sl1 = s0 + 64 + lane;
  const int r0s = sl0 >> 3, c0s = ((sl0 & 7) ^ (r0s & 7)) * 8;
  const int r1s = sl1 >> 3, c1s = ((sl1 & 7) ^ (r1s & 7)) * 8;

  // read-side swizzled chunk offsets (u16 units); row&7 == col&7 for our rows
  const int kx = col & 7;
  int off4[4];
#pragma unroll
  for (int i = 0; i < 4; i++) off4[i] = ((i * 2 + hi) ^ kx) << 3;

  // prologue: stage tile 0 into buffer 0, full drain once
  gl2lds16(Kh + (size_t)r0s * 64 + c0s, KT[0] + (size_t)s0 * 8);
  gl2lds16(Kh + (size_t)r1s * 64 + c1s, KT[0] + (size_t)(s0 + 64) * 8);
  gl2lds16(Vh + (size_t)r0s * 2048 + c0s, VS[0] + (size_t)s0 * 8);
  gl2lds16(Vh + (size_t)r1s * 2048 + c1s, VS[0] + (size_t)(s0 + 64) * 8);
  __syncthreads();

  float lsum = 0.0f;
  facc16 oacc0 = (facc16)0.0f, oacc1 = (facc16)0.0f;

  for (int it = 0; it < 16; ++it) {
    const int t0 = it * 64;
    const int cur = it & 1;
    if (it < 15) {  // issue next tile, then wait for CURRENT tile only
      const int nxt = cur ^ 1;
      const int t0n = t0 + 64;
      gl2lds16(Kh + (size_t)(t0n + r0s) * 64 + c0s, KT[nxt] + (size_t)s0 * 8);
      gl2lds16(Kh + (size_t)(t0n + r1s) * 64 + c1s,
               KT[nxt] + (size_t)(s0 + 64) * 8);
      gl2lds16(Vh + (size_t)r0s * 2048 + t0n + c0s, VS[nxt] + (size_t)s0 * 8);
      gl2lds16(Vh + (size_t)r1s * 2048 + t0n + c1s,
               VS[nxt] + (size_t)(s0 + 64) * 8);
      asm volatile("s_waitcnt vmcnt(4)" ::: "memory");
    } else {
      asm volatile("s_waitcnt vmcnt(0)" ::: "memory");
    }
    __builtin_amdgcn_s_barrier();  // all waves' current tile staged

    const u16* kb = KT[cur];
    const u16* vb = VS[cur];
#pragma unroll
    for (int tile = 0; tile < 2; tile++) {
      // S^T = K * Q^T over Dh=64 (4 k-slices)
      facc16 sacc = (facc16)0.0f;
#pragma unroll
      for (int ds = 0; ds < 4; ds++) {
        bfrag kf = *(const bfrag*)(kb + (tile * 32 + col) * 64 + off4[ds]);
        sacc = mfma32(kf, qf[ds], sacc);
      }
      // in-register softmax + pack; reg r -> key t0+tile*32+(r&3)+8*(r>>2)+4*hi
      u32 w[8];
#pragma unroll
      for (int g = 0; g < 4; g++) {
        const float4 mg = *(const float4*)(MB + t0 + tile * 32 + g * 8 + 4 * hi);
        const float p0 = __builtin_amdgcn_exp2f(fmaf(sacc[g * 4 + 0], SC, mg.x));
        const float p1 = __builtin_amdgcn_exp2f(fmaf(sacc[g * 4 + 1], SC, mg.y));
        const float p2 = __builtin_amdgcn_exp2f(fmaf(sacc[g * 4 + 2], SC, mg.z));
        const float p3 = __builtin_amdgcn_exp2f(fmaf(sacc[g * 4 + 3], SC, mg.w));
        lsum += (p0 + p1) + (p2 + p3);
        w[g * 2 + 0] = pk2(p0, p1);
        w[g * 2 + 1] = pk2(p2, p3);
      }
      // redistribute halves: B-operand needs k = 8*hi + j per 16-key slice
      pswap(w[0], w[2]);
      pswap(w[1], w[3]);
      pswap(w[4], w[6]);
      pswap(w[5], w[7]);
#pragma unroll
      for (int sub = 0; sub < 2; sub++) {
        u32x4 pv4;
        pv4[0] = w[sub * 4 + 0];
        pv4[1] = w[sub * 4 + 1];
        pv4[2] = w[sub * 4 + 2];
        pv4[3] = w[sub * 4 + 3];
        const bfrag pa = __builtin_bit_cast(bfrag, pv4);
        const int ks = tile * 2 + sub;  // 16-key slice index within 64
        {
          bfrag vf = *(const bfrag*)(vb + (0 * 32 + col) * 64 + off4[ks]);
          oacc0 = mfma32(vf, pa, oacc0);
        }
        {
          bfrag vf = *(const bfrag*)(vb + (1 * 32 + col) * 64 + off4[ks]);
          oacc1 = mfma32(vf, pa, oacc1);
        }
      }
    }
    __builtin_amdgcn_s_barrier();  // readers done before next overwrite
  }

  // l(q) = lsum(hi=0) + lsum(hi=1); one writer per q
  const float l = lsum + __shfl_xor(lsum, 32, 64);
  if (hi == 0) lbuf[((size_t)(z * 32 + bh)) * 2048 + q] = l;

  // O^T regs: e = eh*32 + (r&3) + 8*(r>>2) + 4*hi, col = q; pack 4-e runs
  u16* dst = Opart + (size_t)z * 4096 * 1024 +
             ((size_t)(b * 2048 + q)) * 1024 + h * 64;
#pragma unroll
  for (int eh = 0; eh < 2; eh++) {
    const facc16& oa = eh ? oacc1 : oacc0;
#pragma unroll
    for (int g = 0; g < 4; g++) {
      ushort4 pk;
      pk.x = f2bf(oa[g * 4 + 0]);
      pk.y = f2bf(oa[g * 4 + 1]);
      pk.z = f2bf(oa[g * 4 + 2]);
      pk.w = f2bf(oa[g * 4 + 3]);
      *(ushort4*)(dst + eh * 32 + g * 8 + 4 * hi) = pk;
    }
  }
}

// ---------------------------------------------------------------------------
// x1 = x + LN((O0+O1)/(l0+l1)); fused attention combine + LayerNorm.
// O partials bf16. Writes fp32 + bf16 copies.
// ---------------------------------------------------------------------------
__global__ __launch_bounds__(256) void ln_attn(
    const float* __restrict__ base, const u16* __restrict__ Opart,
    const float* __restrict__ lbuf,
    const float* __restrict__ alpha, const float* __restrict__ beta,
    float* __restrict__ outf, u16* __restrict__ outb) {
  __shared__ float red[4];
  const int row = blockIdx.x;           // token = b*2048 + s
  const int t = threadIdx.x;
  const int b = row >> 11, s = row & 2047;
  const int h = t >> 4;                 // head of columns t*4..t*4+3
  const size_t off = (size_t)row * 1024 + t * 4;
  const size_t zstride = (size_t)4096 * 1024;

  const float l0 = lbuf[((size_t)(b * 16 + h)) * 2048 + s];
  const float l1 = lbuf[((size_t)(32 + b * 16 + h)) * 2048 + s];
  const float inv = 1.0f / (l0 + l1);

  const ushort4 o0 = *(const ushort4*)(Opart + off);
  const ushort4 o1 = *(const ushort4*)(Opart + zstride + off);
  float4 yv;
  yv.x = (bf2f(o0.x) + bf2f(o1.x)) * inv;
  yv.y = (bf2f(o0.y) + bf2f(o1.y)) * inv;
  yv.z = (bf2f(o0.z) + bf2f(o1.z)) * inv;
  yv.w = (bf2f(o0.w) + bf2f(o1.w)) * inv;

  float sm = yv.x + yv.y + yv.z + yv.w;
#pragma unroll
  for (int o = 1; o < 64; o <<= 1) sm += __shfl_xor(sm, o, 64);
  if ((t & 63) == 0) red[t >> 6] = sm;
  __syncthreads();
  const float mean = (red[0] + red[1] + red[2] + red[3]) * (1.0f / 1024.0f);
  __syncthreads();

  const float d0 = yv.x - mean, d1 = yv.y - mean, d2 = yv.z - mean, d3 = yv.w - mean;
  float ss = d0 * d0 + d1 * d1 + d2 * d2 + d3 * d3;
#pragma unroll
  for (int o = 1; o < 64; o <<= 1) ss += __shfl_xor(ss, o, 64);
  if ((t & 63) == 0) red[t >> 6] = ss;
  __syncthreads();
  const float var = (red[0] + red[1] + red[2] + red[3]) * (1.0f / 1023.0f);
  const float rstd = 1.0f / (sqrtf(var) + 1e-6f);

  const float4 bv = *(const float4*)(base + off);
  const float4 av = *(const float4*)(alpha + (size_t)t * 4);
  const float4 ev = *(const float4*)(beta + (size_t)t * 4);

  float4 ov;
  ov.x = bv.x + av.x * d0 * rstd + ev.x;
  ov.y = bv.y + av.y * d1 * rstd + ev.y;
  ov.z = bv.z + av.z * d2 * rstd + ev.z;
  ov.w = bv.w + av.w * d3 * rstd + ev.w;
  *(float4*)(outf + off) = ov;
  ushort4 ob;
  ob.x = f2bf(ov.x); ob.y = f2bf(ov.y); ob.z = f2bf(ov.z); ob.w = f2bf(ov.w);
  *(ushort4*)(outb + off) = ob;
}

// Final LN: y = sum of 2 bf16 split-K partials + bias; out fp32.
__global__ __launch_bounds__(256) void ln_res2(
    const float* __restrict__ base, const u16* __restrict__ parts,
    const float* __restrict__ biasv,
    const float* __restrict__ alpha, const float* __restrict__ beta,
    float* __restrict__ outf) {
  __shared__ float red[4];
  const int row = blockIdx.x;
  const int t = threadIdx.x;
  const size_t off = (size_t)row * 1024 + t * 4;
  const size_t stride = (size_t)4096 * 1024;

  float4 yv = *(const float4*)(biasv + (size_t)t * 4);
#pragma unroll
  for (int zi = 0; zi < 2; zi++) {
    const ushort4 pz = *(const ushort4*)(parts + zi * stride + off);
    yv.x += bf2f(pz.x); yv.y += bf2f(pz.y);
    yv.z += bf2f(pz.z); yv.w += bf2f(pz.w);
  }

  float s = yv.x + yv.y + yv.z + yv.w;
#pragma unroll
  for (int o = 1; o < 64; o <<= 1) s += __shfl_xor(s, o, 64);
  if ((t & 63) == 0) red[t >> 6] = s;
  __syncthreads();
  const float mean = (red[0] + red[1] + red[2] + red[3]) * (1.0f / 1024.0f);
  __syncthreads();

  const float d0 = yv.x - mean, d1 = yv.y - mean, d2 = yv.z - mean, d3 = yv.w - mean;
  float ss = d0 * d0 + d1 * d1 + d2 * d2 + d3 * d3;
#pragma unroll
  for (int o = 1; o < 64; o <<= 1) ss += __shfl_xor(ss, o, 64);
  if ((t & 63) == 0) red[t >> 6] = ss;
  __syncthreads();
  const float var = (red[0] + red[1] + red[2] + red[3]) * (1.0f / 1023.0f);
  const float rstd = 1.0f / (sqrtf(var) + 1e-6f);

  const float4 bv = *(const float4*)(base + off);
  const float4 av = *(const float4*)(alpha + (size_t)t * 4);
  const float4 ev = *(const float4*)(beta + (size_t)t * 4);

  float4 ov;
  ov.x = bv.x + av.x * d0 * rstd + ev.x;
  ov.y = bv.y + av.y * d1 * rstd + ev.y;
  ov.z = bv.z + av.z * d2 * rstd + ev.z;
  ov.w = bv.w + av.w * d3 * rstd + ev.w;
  *(float4*)(outf + off) = ov;
}

// ---------------------------------------------------------------------------
extern "C" void kernel_launch(void* const* d_in, const int* in_sizes, int n_in,
                              void* d_out, int out_size, void* d_ws,
                              size_t ws_size, hipStream_t stream) {
  const float* x  = (const float*)d_in[0];
  const int* mask = (const int*)d_in[1];
  const float* Wq = (const float*)d_in[2];
  const float* bq = (const float*)d_in[3];
  const float* Wk = (const float*)d_in[4];
  const float* bk = (const float*)d_in[5];
  const float* Wv = (const float*)d_in[6];
  const float* bv = (const float*)d_in[7];
  const float* W1 = (const float*)d_in[8];
  const float* b1 = (const float*)d_in[9];
  const float* W2 = (const float*)d_in[10];
  const float* b2 = (const float*)d_in[11];
  const float* alpha1 = (const float*)d_in[12];
  const float* beta1  = (const float*)d_in[13];
  const float* alpha2 = (const float*)d_in[14];
  const float* beta2  = (const float*)d_in[15];
  float* out = (float*)d_out;

  // workspace carve-up (bytes), total ~135 MB
  char* p = (char*)d_ws;
  u16* xb      = (u16*)p;  p += (size_t)4096 * 1024 * 2;
  u16* WqkvT   = (u16*)p;  p += (size_t)3072 * 1024 * 2;
  u16* W1T     = (u16*)p;  p += (size_t)4096 * 1024 * 2;
  u16* W2T     = (u16*)p;  p += (size_t)1024 * 4096 * 2;
  u16* Qbuf    = (u16*)p;  p += (size_t)32 * 2048 * 64 * 2;
  u16* Kbuf    = (u16*)p;  p += (size_t)32 * 2048 * 64 * 2;
  u16* Vbuf    = (u16*)p;  p += (size_t)32 * 2048 * 64 * 2;  // V^T [bh][e][s]
  u16* attnp   = (u16*)p;  p += (size_t)2 * 4096 * 1024 * 2;  // bf16 O partials
  float* lbuf  = (float*)p; p += (size_t)2 * 32 * 2048 * 4;   // l partials
  float* x1f   = (float*)p; p += (size_t)4096 * 1024 * 4;
  u16* x1b     = (u16*)p;  p += (size_t)4096 * 1024 * 2;
  u16* hbuf    = (u16*)p;  p += (size_t)4096 * 4096 * 2;
  u16* ffnp    = (u16*)p;  p += (size_t)2 * 4096 * 1024 * 2;  // 2 bf16 partials

  // 1) merged prep: transposes + x cast
  prep_kernel<<<15360, 256, 0, stream>>>(Wq, Wk, Wv, WqkvT, W1, W1T, W2, W2T,
                                         x, xb);

  // 2) fused QKV projection (V written transposed); x = M-tile
  gemm_bt<0><<<dim3(32, 24), 256, 0, stream>>>(
      xb, 1024, WqkvT, 1024, 4096, 3072, 1024, bq, bk, bv, Qbuf, Kbuf, Vbuf);

  // 3) flash attention, 32x32 swapped structure, split-S x2
  attn_kernel<<<dim3(32, 16, 2), 256, 0, stream>>>(Qbuf, Kbuf, Vbuf, mask,
                                                   attnp, lbuf);

  // 4) x1 = x + LN(combine(attn))   (fp32 + bf16 copies)
  ln_attn<<<4096, 256, 0, stream>>>(x, attnp, lbuf, alpha1, beta1, x1f, x1b);

  // 5) h = relu(x1 @ W1 + b1) -> bf16; x = M-tile
  gemm_bt<1><<<dim3(32, 32), 256, 0, stream>>>(
      x1b, 1024, W1T, 1024, 4096, 4096, 1024, b1, nullptr, nullptr,
      hbuf, nullptr, nullptr);

  // 6) ffn partials: h @ W2 split-K x2 -> bf16 partials; x = M-tile
  gemm_bt<3><<<dim3(32, 8, 2), 256, 0, stream>>>(
      hbuf, 4096, W2T, 4096, 4096, 1024, 2048, nullptr, nullptr, nullptr,
      ffnp, nullptr, nullptr);

  // 7) out = x1 + LN(p0+p1 + b2)
  ln_res2<<<4096, 256, 0, stream>>>(x1f, ffnp, b2, alpha2, beta2, out);
}

// Round 2
// 312.786 us; speedup vs baseline: 1.4352x; 1.3116x over previous
//
#include <hip/hip_runtime.h>

// EncoderBlock on MI355X (gfx950). B=2,S=2048,D=1024,H=16,Dh=64.
// Round 10: GEMMs rewritten as 256x256/BK=64 2-phase counted-vmcnt kernel
// (stage next K-step, s_waitcnt vmcnt(8) -- never 0 -- + raw s_barrier;
// row&7 XOR-swizzled LDS staged via pre-swizzled gl2lds source).
// FFN2 now split-K x4 (K=1024 each); partials 2,3 alias the dead attnp buf.

#define DEV __device__ __forceinline__

typedef unsigned short u16;
typedef unsigned int u32;
typedef __attribute__((ext_vector_type(8))) short bfrag;    // 8 bf16 payload
typedef __attribute__((ext_vector_type(8))) __bf16 bf16x8;  // MFMA operand type
typedef __attribute__((ext_vector_type(2))) __bf16 bf16x2_t;
typedef __attribute__((ext_vector_type(4))) unsigned int u32x4;
typedef __attribute__((ext_vector_type(4))) float facc;     // 16x16 MFMA C/D
typedef __attribute__((ext_vector_type(16))) float facc16;  // 32x32 MFMA C/D

DEV float bf2f(u16 u) {
  unsigned int x = ((unsigned int)u) << 16;
  return __builtin_bit_cast(float, x);
}
DEV u16 f2bf(float f) {
  unsigned int x = __builtin_bit_cast(unsigned int, f);
  x += 0x7fffu + ((x >> 16) & 1u);  // RNE
  return (u16)(x >> 16);
}

DEV void gl2lds16(const u16* g, u16* l) {
  // async global->LDS DMA, 16B/lane; LDS dest = wave-uniform base + lane*16
  auto gp = (const __attribute__((address_space(1))) unsigned int*)(g);
  auto lp = (__attribute__((address_space(3))) unsigned int*)(l);
  __builtin_amdgcn_global_load_lds(gp, lp, 16, 0, 0);
}

DEV facc mfma16(bfrag a, bfrag b, facc c) {
  return __builtin_amdgcn_mfma_f32_16x16x32_bf16(
      __builtin_bit_cast(bf16x8, a), __builtin_bit_cast(bf16x8, b), c, 0, 0, 0);
}

DEV facc16 mfma32(bfrag a, bfrag b, facc16 c) {
  return __builtin_amdgcn_mfma_f32_32x32x16_bf16(
      __builtin_bit_cast(bf16x8, a), __builtin_bit_cast(bf16x8, b), c, 0, 0, 0);
}

DEV u32 pk2(float a, float b) {  // pack 2 f32 -> 2 bf16 (RNE, v_cvt_pk path)
  bf16x2_t v;
  v[0] = (__bf16)a;
  v[1] = (__bf16)b;
  return __builtin_bit_cast(u32, v);
}

DEV void pswap(u32& a, u32& b) {  // a' = {a.lo, b.lo}; b' = {a.hi, b.hi}
  asm volatile("v_permlane32_swap_b32 %0, %1" : "+v"(a), "+v"(b));
}

// ---------------------------------------------------------------------------
// Merged prep: qkv transpose (jobs 0..3071), W1T (3072..7167),
// W2T (7168..11263), x cast (11264..15359). All fp32 -> bf16.
// ---------------------------------------------------------------------------
__global__ __launch_bounds__(256) void prep_kernel(
    const float* __restrict__ Wq, const float* __restrict__ Wk,
    const float* __restrict__ Wv, u16* __restrict__ WqkvT,
    const float* __restrict__ W1, u16* __restrict__ W1T,
    const float* __restrict__ W2, u16* __restrict__ W2T,
    const float* __restrict__ x, u16* __restrict__ xb) {
  __shared__ float tile[32][33];
  const int job = blockIdx.x;
  const int tr = threadIdx.x >> 5, tc = threadIdx.x & 31;

  if (job >= 11264) {  // cast x
    const int i = (job - 11264) * 1024 + threadIdx.x * 4;
    const float4 v = *(const float4*)(x + i);
    ushort4 o;
    o.x = f2bf(v.x); o.y = f2bf(v.y); o.z = f2bf(v.z); o.w = f2bf(v.w);
    *(ushort4*)(xb + i) = o;
    return;
  }

  const float* in;
  u16* out;
  int C, R, c0, r0;
  if (job < 3072) {  // qkv: [H][1024][64] -> rows which*1024+h*64+e, cols d
    const int z = job >> 6, rem = job & 63;
    const int which = z >> 4, h = z & 15;
    in = ((which == 0) ? Wq : (which == 1) ? Wk : Wv) + (size_t)h * 1024 * 64;
    out = WqkvT + ((size_t)which * 1024 + h * 64) * 1024;
    C = 64; R = 1024;
    c0 = (rem & 1) * 32; r0 = (rem >> 1) * 32;
  } else if (job < 7168) {  // W1 [1024][4096] -> W1T [4096][1024]
    const int rem = job - 3072;
    in = W1; out = W1T; C = 4096; R = 1024;
    c0 = (rem & 127) * 32; r0 = (rem >> 7) * 32;
  } else {  // W2 [4096][1024] -> W2T [1024][4096]
    const int rem = job - 7168;
    in = W2; out = W2T; C = 1024; R = 4096;
    c0 = (rem & 31) * 32; r0 = (rem >> 5) * 32;
  }
#pragma unroll
  for (int k = 0; k < 4; k++)
    tile[tr + 8 * k][tc] = in[(size_t)(r0 + tr + 8 * k) * C + c0 + tc];
  __syncthreads();
#pragma unroll
  for (int k = 0; k < 4; k++)
    out[(size_t)(c0 + tr + 8 * k) * R + r0 + tc] = f2bf(tile[tc][tr + 8 * k]);
}

// ---------------------------------------------------------------------------
// GEMM C[M][N] = A[M][K] * Bt[N][K]^T, 256x256 tile, BK=64, 8 waves (2Mx4N),
// double-buffered LDS (128 KB) with stage-ahead-by-one K-step and counted
// s_waitcnt vmcnt(8) (never 0 inside the loop) + raw s_barrier.
// LDS layout per matrix: 16B slot s holds (row = s>>3, k-chunk = (s&7)^(row&7))
// -- the row&7 XOR swizzle makes ds_read_b128 of A/B fragments conflict-free;
// staged linearly via pre-swizzled global source addresses.
// MODE 0: QKV scatter +bias -> bf16 (V transposed [bh][e][s], packed stores).
// MODE 1: +bias, ReLU -> bf16.
// MODE 3: split-K partial -> bf16; z<2 -> out0 half z, z>=2 -> out1 half z-2.
// ---------------------------------------------------------------------------
template <int MODE>
__global__ __launch_bounds__(512, 2) void gemm256(
    const u16* __restrict__ A, int lda, const u16* __restrict__ Bt, int ldb,
    int M, int N, int K,
    const float* __restrict__ bias0, const float* __restrict__ bias1,
    const float* __restrict__ bias2,
    void* __restrict__ out0, void* __restrict__ out1, void* __restrict__ out2) {
  __shared__ __align__(16) u16 As[2][256 * 64];  // 2 x 32 KB
  __shared__ __align__(16) u16 Bs[2][256 * 64];  // 2 x 32 KB
  const int tid = threadIdx.x;
  const int lane = tid & 63;
  const int wave = tid >> 6;  // 0..7
  const int laneM = lane & 15, quad = lane >> 4;
  const int kx = laneM & 7;  // read-side swizzle key (row&7 == laneM&7)
  const int m0 = blockIdx.x * 256, n0 = blockIdx.y * 256;
  const int wm = wave & 1, wn = wave >> 1;  // 2 x 4 wave grid

  const u16* Ab = A;
  const u16* Bb = Bt;
  if (MODE == 3) {  // split-K: shift K-origin
    Ab += (size_t)blockIdx.z * K;
    Bb += (size_t)blockIdx.z * K;
  }

  // staging coords: this thread covers slots wave*256 + c*64 + lane, c=0..3
  // (slot -> row = slot>>3, phys chunk = slot&7, logical chunk = phys^(row&7))
  int srow[4], skl[4];
#pragma unroll
  for (int c = 0; c < 4; c++) {
    const int slot = wave * 256 + c * 64 + lane;
    srow[c] = slot >> 3;
    skl[c] = ((slot & 7) ^ (srow[c] & 7)) * 8;
  }

  auto stage = [&](int X, int t) {
    const u16* Asrc = Ab + (size_t)t * 64;
    const u16* Bsrc = Bb + (size_t)t * 64;
#pragma unroll
    for (int c = 0; c < 4; c++)
      gl2lds16(Asrc + (size_t)(m0 + srow[c]) * lda + skl[c],
               As[X] + (size_t)(wave * 256 + c * 64) * 8);
#pragma unroll
    for (int c = 0; c < 4; c++)
      gl2lds16(Bsrc + (size_t)(n0 + srow[c]) * ldb + skl[c],
               Bs[X] + (size_t)(wave * 256 + c * 64) * 8);
  };

  facc acc[8][4] = {};

  const int NT = K >> 6;
  stage(0, 0);  // prologue: 8 loads in flight

  for (int t = 0; t < NT; ++t) {
    const int cur = t & 1;
    if (t + 1 < NT) {
      stage(cur ^ 1, t + 1);  // 8 more loads; buffer freed by last barrier
      asm volatile("s_waitcnt vmcnt(8)" ::: "memory");  // step t landed
    } else {
      asm volatile("s_waitcnt vmcnt(0)" ::: "memory");
    }
    __builtin_amdgcn_s_barrier();  // all waves: buf[cur] fully staged

    const u16* as = As[cur];
    const u16* bs = Bs[cur];
#pragma unroll
    for (int k32 = 0; k32 < 2; ++k32) {
      bfrag af[8], bf[4];
#pragma unroll
      for (int i = 0; i < 8; i++) {
        const int row = wm * 128 + i * 16 + laneM;
        af[i] = *(const bfrag*)(as + row * 64 + (((k32 * 4 + quad) ^ kx) * 8));
      }
#pragma unroll
      for (int j = 0; j < 4; j++) {
        const int row = wn * 64 + j * 16 + laneM;
        bf[j] = *(const bfrag*)(bs + row * 64 + (((k32 * 4 + quad) ^ kx) * 8));
      }
#pragma unroll
      for (int i = 0; i < 8; i++)
#pragma unroll
        for (int j = 0; j < 4; j++)
          acc[i][j] = mfma16(af[i], bf[j], acc[i][j]);
    }
    __builtin_amdgcn_s_barrier();  // readers done before next overwrite
  }

  // epilogue: C/D layout col=lane&15, row=quad*4+v
#pragma unroll
  for (int i = 0; i < 8; i++) {
#pragma unroll
    for (int j = 0; j < 4; j++) {
      const int col = n0 + wn * 64 + j * 16 + laneM;
      const int row0 = m0 + wm * 128 + i * 16 + quad * 4;
      if (MODE == 0) {
        const int which = col >> 10, c = col & 1023;
        const float* bp = (which == 0) ? bias0 : (which == 1) ? bias1 : bias2;
        u16* op = (u16*)((which == 0) ? out0 : (which == 1) ? out1 : out2);
        const float bb = bp[c];
        const int b = row0 >> 11, s0 = row0 & 2047;
        const int h = c >> 6, e = c & 63;
        if (which == 2) {  // V^T [bh][e][s]: 4 consecutive s -> one 8B store
          ushort4 pk;
          pk.x = f2bf(acc[i][j][0] + bb);
          pk.y = f2bf(acc[i][j][1] + bb);
          pk.z = f2bf(acc[i][j][2] + bb);
          pk.w = f2bf(acc[i][j][3] + bb);
          *(ushort4*)(op + ((size_t)((b * 16 + h) * 64 + e)) * 2048 + s0) = pk;
        } else {
#pragma unroll
          for (int v = 0; v < 4; v++)
            op[((size_t)(b * 16 + h) * 2048 + s0 + v) * 64 + e] =
                f2bf(acc[i][j][v] + bb);
        }
      } else if (MODE == 1) {
        const float bb = bias0[col];
#pragma unroll
        for (int v = 0; v < 4; v++)
          ((u16*)out0)[(size_t)(row0 + v) * N + col] =
              f2bf(fmaxf(acc[i][j][v] + bb, 0.0f));
      } else {  // MODE 3: bf16 partial z; z>=2 spills into out1 (aliased buf)
        const int z = blockIdx.z;
        u16* op = (u16*)((z < 2) ? out0 : out1) + (size_t)(z & 1) * M * N;
#pragma unroll
        for (int v = 0; v < 4; v++)
          op[(size_t)(row0 + v) * N + col] = f2bf(acc[i][j][v]);
      }
    }
  }
}

// ---------------------------------------------------------------------------
// Flash attention, 32x32 swapped-operand structure (round-9, verified).
// GRID: x = bh (32), y = Q-tile of 128 rows (16), z = S-half (2).
// ---------------------------------------------------------------------------
__global__ __launch_bounds__(256) void attn_kernel(
    const u16* __restrict__ Qb, const u16* __restrict__ Kb,
    const u16* __restrict__ VTg, const int* __restrict__ mask,
    u16* __restrict__ Opart, float* __restrict__ lbuf) {
  __shared__ __align__(16) u16 KT[2][64 * 64];  // 2 x 8 KB, swizzled rows
  __shared__ __align__(16) u16 VS[2][64 * 64];  // 2 x 8 KB, [e][key] swizzled
  __shared__ float MB[1024];                    // additive mask bias (half)
  const int tid = threadIdx.x;
  const int lane = tid & 63;
  const int wave = tid >> 6;
  const int col = lane & 31, hi = lane >> 5;
  const int bh = blockIdx.x, b = bh >> 4, h = bh & 15;
  const int q0 = blockIdx.y * 128;
  const int z = blockIdx.z;
  const int sbase = z * 1024;
  const u16* Qh = Qb + (size_t)bh * 2048 * 64;
  const u16* Kh = Kb + (size_t)bh * 2048 * 64 + (size_t)sbase * 64;
  const u16* Vh = VTg + (size_t)bh * 64 * 2048 + sbase;
  const float SC = 0.125f * 1.4426950408889634f;  // Dh^-0.5 * log2(e)

  // Q fragments (one global read per slice; B-operand: col=q, k=8*hi+j)
  const int q = q0 + wave * 32 + col;
  bfrag qf[4];
#pragma unroll
  for (int ds = 0; ds < 4; ds++)
    qf[ds] = *(const bfrag*)(Qh + (size_t)q * 64 + ds * 16 + 8 * hi);

  // mask -> additive bias table for this half (once per block)
#pragma unroll
  for (int t = 0; t < 4; t++) {
    const int i = t * 256 + tid;
    MB[i] = mask[b * 2048 + sbase + i] ? 0.0f : -1e30f;
  }

  // staging geometry: phys 16B slot s holds logical (row=s>>3, chunk=(s&7)^(row&7))
  const int s0 = wave * 128;  // this wave's 128-slot strip (2 calls of 64)
  const int sl0 = s0 + lane, sl1 = s0 + 64 + lane;
  const int r0s = sl0 >> 3, c0s = ((sl0 & 7) ^ (r0s & 7)) * 8;
  const int r1s = sl1 >> 3, c1s = ((sl1 & 7) ^ (r1s & 7)) * 8;

  // read-side swizzled chunk offsets (u16 units); row&7 == col&7 for our rows
  const int kx = col & 7;
  int off4[4];
#pragma unroll
  for (int i = 0; i < 4; i++) off4[i] = ((i * 2 + hi) ^ kx) << 3;

  // prologue: stage tile 0 into buffer 0, full drain once
  gl2lds16(Kh + (size_t)r0s * 64 + c0s, KT[0] + (size_t)s0 * 8);
  gl2lds16(Kh + (size_t)r1s * 64 + c1s, KT[0] + (size_t)(s0 + 64) * 8);
  gl2lds16(Vh + (size_t)r0s * 2048 + c0s, VS[0] + (size_t)s0 * 8);
  gl2lds16(Vh + (size_t)r1s * 2048 + c1s, VS[0] + (size_t)(s0 + 64) * 8);
  __syncthreads();

  float lsum = 0.0f;
  facc16 oacc0 = (facc16)0.0f, oacc1 = (facc16)0.0f;

  for (int it = 0; it < 16; ++it) {
    const int t0 = it * 64;
    const int cur = it & 1;
    if (it < 15) {  // issue next tile, then wait for CURRENT tile only
      const int nxt = cur ^ 1;
      const int t0n = t0 + 64;
      gl2lds16(Kh + (size_t)(t0n + r0s) * 64 + c0s, KT[nxt] + (size_t)s0 * 8);
      gl2lds16(Kh + (size_t)(t0n + r1s) * 64 + c1s,
               KT[nxt] + (size_t)(s0 + 64) * 8);
      gl2lds16(Vh + (size_t)r0s * 2048 + t0n + c0s, VS[nxt] + (size_t)s0 * 8);
      gl2lds16(Vh + (size_t)r1s * 2048 + t0n + c1s,
               VS[nxt] + (size_t)(s0 + 64) * 8);
      asm volatile("s_waitcnt vmcnt(4)" ::: "memory");
    } else {
      asm volatile("s_waitcnt vmcnt(0)" ::: "memory");
    }
    __builtin_amdgcn_s_barrier();  // all waves' current tile staged

    const u16* kb = KT[cur];
    const u16* vb = VS[cur];
#pragma unroll
    for (int tile = 0; tile < 2; tile++) {
      // S^T = K * Q^T over Dh=64 (4 k-slices)
      facc16 sacc = (facc16)0.0f;
#pragma unroll
      for (int ds = 0; ds < 4; ds++) {
        bfrag kf = *(const bfrag*)(kb + (tile * 32 + col) * 64 + off4[ds]);
        sacc = mfma32(kf, qf[ds], sacc);
      }
      // in-register softmax + pack; reg r -> key t0+tile*32+(r&3)+8*(r>>2)+4*hi
      u32 w[8];
#pragma unroll
      for (int g = 0; g < 4; g++) {
        const float4 mg = *(const float4*)(MB + t0 + tile * 32 + g * 8 + 4 * hi);
        const float p0 = __builtin_amdgcn_exp2f(fmaf(sacc[g * 4 + 0], SC, mg.x));
        const float p1 = __builtin_amdgcn_exp2f(fmaf(sacc[g * 4 + 1], SC, mg.y));
        const float p2 = __builtin_amdgcn_exp2f(fmaf(sacc[g * 4 + 2], SC, mg.z));
        const float p3 = __builtin_amdgcn_exp2f(fmaf(sacc[g * 4 + 3], SC, mg.w));
        lsum += (p0 + p1) + (p2 + p3);
        w[g * 2 + 0] = pk2(p0, p1);
        w[g * 2 + 1] = pk2(p2, p3);
      }
      // redistribute halves: B-operand needs k = 8*hi + j per 16-key slice
      pswap(w[0], w[2]);
      pswap(w[1], w[3]);
      pswap(w[4], w[6]);
      pswap(w[5], w[7]);
#pragma unroll
      for (int sub = 0; sub < 2; sub++) {
        u32x4 pv4;
        pv4[0] = w[sub * 4 + 0];
        pv4[1] = w[sub * 4 + 1];
        pv4[2] = w[sub * 4 + 2];
        pv4[3] = w[sub * 4 + 3];
        const bfrag pa = __builtin_bit_cast(bfrag, pv4);
        const int ks = tile * 2 + sub;  // 16-key slice index within 64
        {
          bfrag vf = *(const bfrag*)(vb + (0 * 32 + col) * 64 + off4[ks]);
          oacc0 = mfma32(vf, pa, oacc0);
        }
        {
          bfrag vf = *(const bfrag*)(vb + (1 * 32 + col) * 64 + off4[ks]);
          oacc1 = mfma32(vf, pa, oacc1);
        }
      }
    }
    __builtin_amdgcn_s_barrier();  // readers done before next overwrite
  }

  // l(q) = lsum(hi=0) + lsum(hi=1); one writer per q
  const float l = lsum + __shfl_xor(lsum, 32, 64);
  if (hi == 0) lbuf[((size_t)(z * 32 + bh)) * 2048 + q] = l;

  // O^T regs: e = eh*32 + (r&3) + 8*(r>>2) + 4*hi, col = q; pack 4-e runs
  u16* dst = Opart + (size_t)z * 4096 * 1024 +
             ((size_t)(b * 2048 + q)) * 1024 + h * 64;
#pragma unroll
  for (int eh = 0; eh < 2; eh++) {
    const facc16& oa = eh ? oacc1 : oacc0;
#pragma unroll
    for (int g = 0; g < 4; g++) {
      ushort4 pk;
      pk.x = f2bf(oa[g * 4 + 0]);
      pk.y = f2bf(oa[g * 4 + 1]);
      pk.z = f2bf(oa[g * 4 + 2]);
      pk.w = f2bf(oa[g * 4 + 3]);
      *(ushort4*)(dst + eh * 32 + g * 8 + 4 * hi) = pk;
    }
  }
}

// ---------------------------------------------------------------------------
// x1 = x + LN((O0+O1)/(l0+l1)); fused attention combine + LayerNorm.
// ---------------------------------------------------------------------------
__global__ __launch_bounds__(256) void ln_attn(
    const float* __restrict__ base, const u16* __restrict__ Opart,
    const float* __restrict__ lbuf,
    const float* __restrict__ alpha, const float* __restrict__ beta,
    float* __restrict__ outf, u16* __restrict__ outb) {
  __shared__ float red[4];
  const int row = blockIdx.x;           // token = b*2048 + s
  const int t = threadIdx.x;
  const int b = row >> 11, s = row & 2047;
  const int h = t >> 4;                 // head of columns t*4..t*4+3
  const size_t off = (size_t)row * 1024 + t * 4;
  const size_t zstride = (size_t)4096 * 1024;

  const float l0 = lbuf[((size_t)(b * 16 + h)) * 2048 + s];
  const float l1 = lbuf[((size_t)(32 + b * 16 + h)) * 2048 + s];
  const float inv = 1.0f / (l0 + l1);

  const ushort4 o0 = *(const ushort4*)(Opart + off);
  const ushort4 o1 = *(const ushort4*)(Opart + zstride + off);
  float4 yv;
  yv.x = (bf2f(o0.x) + bf2f(o1.x)) * inv;
  yv.y = (bf2f(o0.y) + bf2f(o1.y)) * inv;
  yv.z = (bf2f(o0.z) + bf2f(o1.z)) * inv;
  yv.w = (bf2f(o0.w) + bf2f(o1.w)) * inv;

  float sm = yv.x + yv.y + yv.z + yv.w;
#pragma unroll
  for (int o = 1; o < 64; o <<= 1) sm += __shfl_xor(sm, o, 64);
  if ((t & 63) == 0) red[t >> 6] = sm;
  __syncthreads();
  const float mean = (red[0] + red[1] + red[2] + red[3]) * (1.0f / 1024.0f);
  __syncthreads();

  const float d0 = yv.x - mean, d1 = yv.y - mean, d2 = yv.z - mean, d3 = yv.w - mean;
  float ss = d0 * d0 + d1 * d1 + d2 * d2 + d3 * d3;
#pragma unroll
  for (int o = 1; o < 64; o <<= 1) ss += __shfl_xor(ss, o, 64);
  if ((t & 63) == 0) red[t >> 6] = ss;
  __syncthreads();
  const float var = (red[0] + red[1] + red[2] + red[3]) * (1.0f / 1023.0f);
  const float rstd = 1.0f / (sqrtf(var) + 1e-6f);

  const float4 bv = *(const float4*)(base + off);
  const float4 av = *(const float4*)(alpha + (size_t)t * 4);
  const float4 ev = *(const float4*)(beta + (size_t)t * 4);

  float4 ov;
  ov.x = bv.x + av.x * d0 * rstd + ev.x;
  ov.y = bv.y + av.y * d1 * rstd + ev.y;
  ov.z = bv.z + av.z * d2 * rstd + ev.z;
  ov.w = bv.w + av.w * d3 * rstd + ev.w;
  *(float4*)(outf + off) = ov;
  ushort4 ob;
  ob.x = f2bf(ov.x); ob.y = f2bf(ov.y); ob.z = f2bf(ov.z); ob.w = f2bf(ov.w);
  *(ushort4*)(outb + off) = ob;
}

// Final LN: y = sum of 4 bf16 split-K partials (2 in each buffer) + bias.
__global__ __launch_bounds__(256) void ln_res2(
    const float* __restrict__ base, const u16* __restrict__ parts0,
    const u16* __restrict__ parts1, const float* __restrict__ biasv,
    const float* __restrict__ alpha, const float* __restrict__ beta,
    float* __restrict__ outf) {
  __shared__ float red[4];
  const int row = blockIdx.x;
  const int t = threadIdx.x;
  const size_t off = (size_t)row * 1024 + t * 4;
  const size_t stride = (size_t)4096 * 1024;

  float4 yv = *(const float4*)(biasv + (size_t)t * 4);
#pragma unroll
  for (int zi = 0; zi < 2; zi++) {
    const ushort4 pz = *(const ushort4*)(parts0 + zi * stride + off);
    yv.x += bf2f(pz.x); yv.y += bf2f(pz.y);
    yv.z += bf2f(pz.z); yv.w += bf2f(pz.w);
  }
#pragma unroll
  for (int zi = 0; zi < 2; zi++) {
    const ushort4 pz = *(const ushort4*)(parts1 + zi * stride + off);
    yv.x += bf2f(pz.x); yv.y += bf2f(pz.y);
    yv.z += bf2f(pz.z); yv.w += bf2f(pz.w);
  }

  float s = yv.x + yv.y + yv.z + yv.w;
#pragma unroll
  for (int o = 1; o < 64; o <<= 1) s += __shfl_xor(s, o, 64);
  if ((t & 63) == 0) red[t >> 6] = s;
  __syncthreads();
  const float mean = (red[0] + red[1] + red[2] + red[3]) * (1.0f / 1024.0f);
  __syncthreads();

  const float d0 = yv.x - mean, d1 = yv.y - mean, d2 = yv.z - mean, d3 = yv.w - mean;
  float ss = d0 * d0 + d1 * d1 + d2 * d2 + d3 * d3;
#pragma unroll
  for (int o = 1; o < 64; o <<= 1) ss += __shfl_xor(ss, o, 64);
  if ((t & 63) == 0) red[t >> 6] = ss;
  __syncthreads();
  const float var = (red[0] + red[1] + red[2] + red[3]) * (1.0f / 1023.0f);
  const float rstd = 1.0f / (sqrtf(var) + 1e-6f);

  const float4 bv = *(const float4*)(base + off);
  const float4 av = *(const float4*)(alpha + (size_t)t * 4);
  const float4 ev = *(const float4*)(beta + (size_t)t * 4);

  float4 ov;
  ov.x = bv.x + av.x * d0 * rstd + ev.x;
  ov.y = bv.y + av.y * d1 * rstd + ev.y;
  ov.z = bv.z + av.z * d2 * rstd + ev.z;
  ov.w = bv.w + av.w * d3 * rstd + ev.w;
  *(float4*)(outf + off) = ov;
}

// ---------------------------------------------------------------------------
extern "C" void kernel_launch(void* const* d_in, const int* in_sizes, int n_in,
                              void* d_out, int out_size, void* d_ws,
                              size_t ws_size, hipStream_t stream) {
  const float* x  = (const float*)d_in[0];
  const int* mask = (const int*)d_in[1];
  const float* Wq = (const float*)d_in[2];
  const float* bq = (const float*)d_in[3];
  const float* Wk = (const float*)d_in[4];
  const float* bk = (const float*)d_in[5];
  const float* Wv = (const float*)d_in[6];
  const float* bv = (const float*)d_in[7];
  const float* W1 = (const float*)d_in[8];
  const float* b1 = (const float*)d_in[9];
  const float* W2 = (const float*)d_in[10];
  const float* b2 = (const float*)d_in[11];
  const float* alpha1 = (const float*)d_in[12];
  const float* beta1  = (const float*)d_in[13];
  const float* alpha2 = (const float*)d_in[14];
  const float* beta2  = (const float*)d_in[15];
  float* out = (float*)d_out;

  // workspace carve-up (bytes), total ~142 MB
  char* p = (char*)d_ws;
  u16* xb      = (u16*)p;  p += (size_t)4096 * 1024 * 2;
  u16* WqkvT   = (u16*)p;  p += (size_t)3072 * 1024 * 2;
  u16* W1T     = (u16*)p;  p += (size_t)4096 * 1024 * 2;
  u16* W2T     = (u16*)p;  p += (size_t)1024 * 4096 * 2;
  u16* Qbuf    = (u16*)p;  p += (size_t)32 * 2048 * 64 * 2;
  u16* Kbuf    = (u16*)p;  p += (size_t)32 * 2048 * 64 * 2;
  u16* Vbuf    = (u16*)p;  p += (size_t)32 * 2048 * 64 * 2;  // V^T [bh][e][s]
  u16* attnp   = (u16*)p;  p += (size_t)2 * 4096 * 1024 * 2;  // bf16 O partials
  float* lbuf  = (float*)p; p += (size_t)2 * 32 * 2048 * 4;   // l partials
  float* x1f   = (float*)p; p += (size_t)4096 * 1024 * 4;
  u16* x1b     = (u16*)p;  p += (size_t)4096 * 1024 * 2;
  u16* hbuf    = (u16*)p;  p += (size_t)4096 * 4096 * 2;
  u16* ffnp    = (u16*)p;  p += (size_t)2 * 4096 * 1024 * 2;  // 2 bf16 partials
  // FFN2 partials z=2,3 alias attnp (dead after ln_attn).

  // 1) merged prep: transposes + x cast
  prep_kernel<<<15360, 256, 0, stream>>>(Wq, Wk, Wv, WqkvT, W1, W1T, W2, W2T,
                                         x, xb);

  // 2) fused QKV projection (V written transposed)
  gemm256<0><<<dim3(16, 12), 512, 0, stream>>>(
      xb, 1024, WqkvT, 1024, 4096, 3072, 1024, bq, bk, bv, Qbuf, Kbuf, Vbuf);

  // 3) flash attention, 32x32 swapped structure, split-S x2
  attn_kernel<<<dim3(32, 16, 2), 256, 0, stream>>>(Qbuf, Kbuf, Vbuf, mask,
                                                   attnp, lbuf);

  // 4) x1 = x + LN(combine(attn))   (fp32 + bf16 copies)
  ln_attn<<<4096, 256, 0, stream>>>(x, attnp, lbuf, alpha1, beta1, x1f, x1b);

  // 5) h = relu(x1 @ W1 + b1) -> bf16
  gemm256<1><<<dim3(16, 16), 512, 0, stream>>>(
      x1b, 1024, W1T, 1024, 4096, 4096, 1024, b1, nullptr, nullptr,
      hbuf, nullptr, nullptr);

  // 6) ffn partials: h @ W2 split-K x4 -> bf16 partials (ffnp + attnp alias)
  gemm256<3><<<dim3(16, 4, 4), 512, 0, stream>>>(
      hbuf, 4096, W2T, 4096, 4096, 1024, 1024, nullptr, nullptr, nullptr,
      ffnp, attnp, nullptr);

  // 7) out = x1 + LN(p0+p1+p2+p3 + b2)
  ln_res2<<<4096, 256, 0, stream>>>(x1f, ffnp, attnp, b2, alpha2, beta2, out);
}